// Round 1
// baseline (238.934 us; speedup 1.0000x reference)
//
#include <hip/hip_runtime.h>
#include <hip/hip_bf16.h>

// Problem constants
#define BATCH 32
#define CIN   128
#define COUT  256
#define HH    56
#define WW    56
#define HP    58    // padded height (one halo row each side)
#define WP    64    // padded width  (halo col + round up to 64)

#define WT_ELEMS   (9 * 256 * 128)            // bf16 weights, tap-major
#define XPAD_ELEMS (32 * 128 * 58 * 64)       // bf16 padded input

typedef __attribute__((ext_vector_type(8))) __bf16 bf16x8;
typedef __attribute__((ext_vector_type(4))) float   f32x4;
typedef __attribute__((ext_vector_type(8))) unsigned short u16x8;

// ---- prep: weight[cout][cin][kh][kw] - wz  ->  wt[r][cout][cin] (bf16 bits) ----
__global__ void wprep_kernel(const float* __restrict__ w, const float* __restrict__ wzp,
                             unsigned short* __restrict__ wt) {
    int t = blockIdx.x * 256 + threadIdx.x;      // < 294912
    int cin  = t & 127;
    int cout = (t >> 7) & 255;
    int r    = t >> 15;                          // 0..8
    float v = w[cout * 1152 + cin * 9 + r] - *wzp;
    // values are exact small integers -> truncation to bf16 is exact
    wt[t] = (unsigned short)(__float_as_uint(v) >> 16);
}

// ---- prep: x - xz, zero-padded -> xpad[b][c][58][64] (bf16 bits) ----
__global__ void xprep_kernel(const float* __restrict__ x, const float* __restrict__ xzp,
                             unsigned short* __restrict__ xp) {
    int t = blockIdx.x * 256 + threadIdx.x;      // < 15,204,352
    int ww = t & 63;
    int hh = (t >> 6) % 58;
    int bc = t / (64 * 58);                      // b*128 + c
    int h = hh - 1, w = ww - 1;
    float v = 0.0f;
    if ((unsigned)h < 56u && (unsigned)w < 56u)
        v = x[bc * 3136 + h * 56 + w] - *xzp;
    xp[t] = (unsigned short)(__float_as_uint(v) >> 16);
}

// ---- main: implicit GEMM, tile 64m x 128n, K = 9 taps x 128 cin ----
__global__ __launch_bounds__(256)
void conv_kernel(const unsigned short* __restrict__ wt,
                 const unsigned short* __restrict__ xp,
                 const float* __restrict__ bias,
                 const float* __restrict__ Mp,
                 const float* __restrict__ yzp,
                 float* __restrict__ out) {
    // LDS stride 40 elems (80B): b128 fragment reads land 2-way max (free)
    __shared__ unsigned short As[64 * 40];
    __shared__ unsigned short Bs[128 * 40];

    const int tid = threadIdx.x;
    const int bh  = blockIdx.x;                  // b*56 + h
    const int nt  = blockIdx.y;                  // cout tile (0..1)
    const int b   = bh / 56;
    const int h   = bh % 56;

    // A staging: thread -> (cin_local 0..31, m0 = 8-aligned)
    const int s_cin = tid >> 3;
    const int s_m0  = (tid & 7) * 8;
    // B staging: thread -> (n 0..127, k-half)
    const int s_n  = tid >> 1;
    const int s_ks = (tid & 1) * 16;

    const int lane = tid & 63;
    const int wid  = tid >> 6;
    const int wm   = wid >> 1;                   // 0..1 (m half)
    const int wn   = wid & 1;                    // 0..1 (n half)
    const int l15  = lane & 15;
    const int lg   = lane >> 4;

    f32x4 acc[2][4];
#pragma unroll
    for (int i = 0; i < 2; ++i)
#pragma unroll
        for (int j = 0; j < 4; ++j)
            acc[i][j] = (f32x4){0.f, 0.f, 0.f, 0.f};

    const unsigned short* xbase = xp + (size_t)b * (128 * 58 * 64);

#pragma unroll
    for (int r = 0; r < 9; ++r) {
        const int kh = r / 3, kw = r % 3;        // compile-time (loop unrolled)
#pragma unroll
        for (int kc = 0; kc < 4; ++kc) {
            __syncthreads();                     // protect LDS from prev compute
            // ---- stage A: As[m][cin] = xpad[b][kc*32+cin][h+kh][m+kw] ----
            {
                const unsigned short* rowp =
                    xbase + ((kc * 32 + s_cin) * 58 + (h + kh)) * 64 + s_m0;
                u16x8 v0 = *reinterpret_cast<const u16x8*>(rowp);
                unsigned int tl = (kw > 0) ? *reinterpret_cast<const unsigned int*>(rowp + 8) : 0u;
                unsigned short t0 = (unsigned short)(tl & 0xffffu);
                unsigned short t1 = (unsigned short)(tl >> 16);
#pragma unroll
                for (int i = 0; i < 8; ++i) {
                    unsigned short e;
                    if (i + kw < 8)      e = (unsigned short)v0[i + kw];
                    else if (i + kw == 8) e = t0;
                    else                  e = t1;
                    As[(s_m0 + i) * 40 + s_cin] = e;
                }
            }
            // ---- stage B: Bs[n][k] = wt[r][nt*128+n][kc*32+k] ----
            {
                const unsigned short* bp =
                    wt + r * 32768 + (nt * 128 + s_n) * 128 + kc * 32 + s_ks;
                u16x8 w0 = *reinterpret_cast<const u16x8*>(bp);
                u16x8 w1 = *reinterpret_cast<const u16x8*>(bp + 8);
                *reinterpret_cast<u16x8*>(&Bs[s_n * 40 + s_ks])     = w0;
                *reinterpret_cast<u16x8*>(&Bs[s_n * 40 + s_ks + 8]) = w1;
            }
            __syncthreads();
            // ---- compute: 2 A-frags x 4 B-frags ----
            bf16x8 a0 = *reinterpret_cast<const bf16x8*>(&As[(wm * 32 + l15) * 40 + lg * 8]);
            bf16x8 a1 = *reinterpret_cast<const bf16x8*>(&As[(wm * 32 + 16 + l15) * 40 + lg * 8]);
#pragma unroll
            for (int fn = 0; fn < 4; ++fn) {
                bf16x8 bf = *reinterpret_cast<const bf16x8*>(
                    &Bs[(wn * 64 + fn * 16 + l15) * 40 + lg * 8]);
                acc[0][fn] = __builtin_amdgcn_mfma_f32_16x16x32_bf16(a0, bf, acc[0][fn], 0, 0, 0);
                acc[1][fn] = __builtin_amdgcn_mfma_f32_16x16x32_bf16(a1, bf, acc[1][fn], 0, 0, 0);
            }
        }
    }

    // ---- epilogue: requantize + ReLU + round ----
    const float Mv  = *Mp;
    const float yzv = *yzp;
#pragma unroll
    for (int fn = 0; fn < 4; ++fn) {
        const int cout = nt * 128 + wn * 64 + fn * 16 + l15;
        const float bv = bias[cout];
#pragma unroll
        for (int fm = 0; fm < 2; ++fm) {
#pragma unroll
            for (int reg = 0; reg < 4; ++reg) {
                const int m = wm * 32 + fm * 16 + lg * 4 + reg;   // w coordinate
                if (m < 56) {
                    float v = (acc[fm][fn][reg] + bv) * Mv + yzv;
                    v = fmaxf(v, yzv);
                    out[(((size_t)b * 256 + cout) * 56 + h) * 56 + m] = rintf(v);
                }
            }
        }
    }
}

extern "C" void kernel_launch(void* const* d_in, const int* in_sizes, int n_in,
                              void* d_out, int out_size, void* d_ws, size_t ws_size,
                              hipStream_t stream) {
    const float* x    = (const float*)d_in[0];
    const float* w    = (const float*)d_in[1];
    const float* bias = (const float*)d_in[2];
    const float* Mp   = (const float*)d_in[3];
    const float* xzp  = (const float*)d_in[4];
    const float* wzp  = (const float*)d_in[5];
    const float* yzp  = (const float*)d_in[6];
    float* out = (float*)d_out;

    unsigned short* wt   = (unsigned short*)d_ws;            // 589,824 B
    unsigned short* xpad = wt + WT_ELEMS;                    // 30,408,704 B (+ tiny slack read OK)

    wprep_kernel<<<WT_ELEMS / 256, 256, 0, stream>>>(w, wzp, wt);
    xprep_kernel<<<XPAD_ELEMS / 256, 256, 0, stream>>>(x, xzp, xpad);

    dim3 grid(BATCH * HH, 2);                                // 1792 x 2
    conv_kernel<<<grid, 256, 0, stream>>>(wt, xpad, bias, Mp, yzp, out);
}

// Round 5
// 123.619 us; speedup vs baseline: 1.9328x; 1.9328x over previous
//
#include <hip/hip_runtime.h>
#include <hip/hip_bf16.h>

// Geometry: B=32, Cin=128, Cout=256, H=W=56, K=3, pad=1, stride=1
// Implicit GEMM: M = B*H*Wpad(64), N = 256, K = 9 taps * 128 cin
//
// xpad2 layout (NHWC, swizzled): per (b,hh) a 16KB row-blob:
//   byte(w, c) = w*256 + ((c*2) ^ ((w&7)<<4)),  w in [0,64), c in [0,128)
//   (x - x_zero) as bf16 bits; zero padding baked in (hh=0/57, w=0 or w>56).
// wt2 layout: per (r, kc, nh) an 8KB blob, 64 rows of 128B pairing n and n+64:
//   byte(n, k) = rr*128 + (((n>>6 &1)*64 + k2) ^ ((rr&7)<<4)),
//   rr = n&63, k2 = (k - kc*32)*2,  value = (w - w_zero) as bf16 bits.
// Both swizzles are involutions; conv reads with the same formula, so
// global_load_lds with a LINEAR dest yields swizzled LDS (rule #21).

typedef __attribute__((ext_vector_type(8))) __bf16 bf16x8;
typedef __attribute__((ext_vector_type(4))) float f32x4;
typedef __attribute__((ext_vector_type(8))) unsigned short u16x8;

#define WT2_ELEMS (9 * 4 * 2 * 4096)     // 294,912 u16 = 576 KB
#define XP_ELEMS  (32 * 58 * 8192)       // 15,204,352 u16 = ~30.4 MB

__device__ __forceinline__ void gload_lds16(const void* g, void* l) {
    __builtin_amdgcn_global_load_lds(
        (const __attribute__((address_space(1))) void*)g,
        (__attribute__((address_space(3))) void*)l, 16, 0, 0);
}

// ---- weight prep: w[cout][cin][3][3] - wz -> wt2 blobs (swizzle-baked) ----
__global__ void wprep_kernel(const float* __restrict__ w, const float* __restrict__ wzp,
                             unsigned short* __restrict__ wt2) {
    int t = blockIdx.x * 256 + threadIdx.x;      // < 294912
    int blobi = t >> 12;                         // (r*4+kc)*2 + nh
    int e = t & 4095;
    int byte = e * 2;
    int rr = byte >> 7;                          // row 0..63
    int slot = byte & 127;
    int us = slot ^ ((rr & 7) << 4);             // un-swizzle
    int hi = (us >> 6) & 1;
    int kl = (us & 63) >> 1;                     // k within chunk 0..31
    int nh = blobi & 1;
    int s  = blobi >> 1;
    int kc = s & 3, r = s >> 2;
    int n = nh * 128 + hi * 64 + rr;
    int k = kc * 32 + kl;
    float v = w[(size_t)n * 1152 + k * 9 + r] - *wzp;
    wt2[t] = (unsigned short)(__float_as_uint(v) >> 16);   // exact (small ints)
}

// ---- x prep: NCHW -> swizzled padded NHWC bf16 ----
__global__ void xprep_kernel(const float* __restrict__ x, const float* __restrict__ xzp,
                             unsigned short* __restrict__ xp) {
    int bhh = blockIdx.x;                        // b*58 + hh
    int b = bhh / 58, hh = bhh % 58;
    int t = threadIdx.x;
    char* blob = (char*)(xp + (size_t)bhh * 8192);
    if (hh == 0 || hh == 57) {
        u16x8 z = {0, 0, 0, 0, 0, 0, 0, 0};
#pragma unroll
        for (int i = 0; i < 4; ++i)
            *(u16x8*)(blob + (i * 256 + t) * 16) = z;
        return;
    }
    int h = hh - 1;
    float xz = *xzp;
    const float* xb = x + (size_t)b * 128 * 3136 + h * 56;   // + c*3136 + w
#pragma unroll
    for (int i = 0; i < 4; ++i) {
        int chunk = i * 256 + t;                 // 0..1023
        int byte = chunk * 16;
        int w = byte >> 8;                       // 0..63
        int slot = byte & 255;
        int c2 = slot ^ ((w & 7) << 4);          // un-swizzle -> source c
        int c0 = c2 >> 1;
        int wsrc = w - 1;
        bool valid = (unsigned)wsrc < 56u;
        u16x8 v;
#pragma unroll
        for (int j = 0; j < 8; ++j) {
            float f = valid ? (xb[(size_t)(c0 + j) * 3136 + wsrc] - xz) : 0.0f;
            v[j] = (unsigned short)(__float_as_uint(f) >> 16);
        }
        *(u16x8*)(blob + byte) = v;
    }
}

// ---- main conv: 128m x 128n tile, 4 waves of 64x64, A resident, B dbuf ----
__global__ __launch_bounds__(256, 2)
void conv_kernel(const unsigned short* __restrict__ wt2,
                 const unsigned short* __restrict__ xp,
                 const float* __restrict__ bias,
                 const float* __restrict__ Mp,
                 const float* __restrict__ yzp,
                 float* __restrict__ out) {
    __shared__ __align__(1024) char smem[81920];     // A 64KB + B 2x8KB
    char* As = smem;
    char* Bs = smem + 65536;

    const int tid = threadIdx.x;
    const int lane = tid & 63;
    const int wid = tid >> 6;
    const int l15 = lane & 15, lg = lane >> 4;
    const int wm = wid >> 1, wn = wid & 1;           // wave: 64m x 64n
    const int bx = blockIdx.x;                       // b*28 + hp
    const int nt = blockIdx.y;                       // cout half
    const int b = bx / 28;
    const int h0 = (bx % 28) * 2;

    // ---- prologue: stage A (4 consecutive row-blobs = 64KB) + B step 0 ----
    const char* agbase = (const char*)xp + (size_t)(b * 58 + h0) * 16384;
    const char* wgbase = (const char*)wt2;
#pragma unroll
    for (int i = 0; i < 16; ++i) {
        int off = i * 4096 + wid * 1024;
        gload_lds16(agbase + off + lane * 16, As + off);
    }
    {
        const char* src = wgbase + (size_t)(0 * 2 + nt) * 8192;
        gload_lds16(src + wid * 1024 + lane * 16, Bs + wid * 1024);
        gload_lds16(src + 4096 + wid * 1024 + lane * 16, Bs + 4096 + wid * 1024);
    }

    f32x4 acc[4][4];
#pragma unroll
    for (int i = 0; i < 4; ++i)
#pragma unroll
        for (int j = 0; j < 4; ++j)
            acc[i][j] = (f32x4){0.f, 0.f, 0.f, 0.f};

    __syncthreads();                                 // drains vmcnt, A+B0 ready

#pragma unroll
    for (int kh = 0; kh < 3; ++kh) {
#pragma unroll
        for (int kw = 0; kw < 3; ++kw) {
#pragma unroll
            for (int kc = 0; kc < 4; ++kc) {
                const int sidx = (kh * 3 + kw) * 4 + kc;
                // prefetch next B chunk into the other buffer
                if (sidx < 35) {
                    const char* src = wgbase + (size_t)((sidx + 1) * 2 + nt) * 8192;
                    char* dst = Bs + ((sidx + 1) & 1) * 8192;
                    gload_lds16(src + wid * 1024 + lane * 16, dst + wid * 1024);
                    gload_lds16(src + 4096 + wid * 1024 + lane * 16,
                                dst + 4096 + wid * 1024);
                }
                // A fragments (4 x 16m), swizzled read
                bf16x8 af[4];
#pragma unroll
                for (int fm = 0; fm < 4; ++fm) {
                    int w = fm * 16 + l15 + kw;
                    int wc = w > 63 ? 63 : w;        // clamped lanes are dead/zero
                    int abyte = (wm + kh) * 16384 + wc * 256 +
                                ((kc * 64 + lg * 16) ^ ((wc & 7) << 4));
                    af[fm] = *(const bf16x8*)(As + abyte);
                }
                // B fragments (4 x 16n)
                bf16x8 bfr[4];
#pragma unroll
                for (int fn = 0; fn < 4; ++fn) {
                    int rr = fn * 16 + l15;
                    int bbyte = (sidx & 1) * 8192 + rr * 128 +
                                ((wn * 64 + lg * 16) ^ ((rr & 7) << 4));
                    bfr[fn] = *(const bf16x8*)(Bs + bbyte);
                }
#pragma unroll
                for (int fm = 0; fm < 4; ++fm)
#pragma unroll
                    for (int fn = 0; fn < 4; ++fn)
                        acc[fm][fn] = __builtin_amdgcn_mfma_f32_16x16x32_bf16(
                            af[fm], bfr[fn], acc[fm][fn], 0, 0, 0);
                __syncthreads();                     // drain prefetch + WAR guard
            }
        }
    }

    // ---- epilogue: requantize + ReLU + round ----
    const float Mv = *Mp;
    const float yzv = *yzp;
#pragma unroll
    for (int fn = 0; fn < 4; ++fn) {
        const int cout = nt * 128 + wn * 64 + fn * 16 + l15;
        const float bv = bias[cout];
        const int h = h0 + wm;
        const size_t rowb = ((size_t)(b * 256 + cout) * 56 + h) * 56;
#pragma unroll
        for (int fm = 0; fm < 4; ++fm) {
#pragma unroll
            for (int reg = 0; reg < 4; ++reg) {
                int w = fm * 16 + lg * 4 + reg;
                if (w < 56) {
                    float v = (acc[fm][fn][reg] + bv) * Mv + yzv;
                    v = fmaxf(v, yzv);
                    out[rowb + w] = rintf(v);
                }
            }
        }
    }
}

extern "C" void kernel_launch(void* const* d_in, const int* in_sizes, int n_in,
                              void* d_out, int out_size, void* d_ws, size_t ws_size,
                              hipStream_t stream) {
    const float* x    = (const float*)d_in[0];
    const float* w    = (const float*)d_in[1];
    const float* bias = (const float*)d_in[2];
    const float* Mp   = (const float*)d_in[3];
    const float* xzp  = (const float*)d_in[4];
    const float* wzp  = (const float*)d_in[5];
    const float* yzp  = (const float*)d_in[6];
    float* out = (float*)d_out;

    unsigned short* wt2 = (unsigned short*)d_ws;           // 576 KB
    unsigned short* xp  = wt2 + WT2_ELEMS;                 // ~30.4 MB

    wprep_kernel<<<WT2_ELEMS / 256, 256, 0, stream>>>(w, wzp, wt2);
    xprep_kernel<<<32 * 58, 256, 0, stream>>>(x, xzp, xp);

    dim3 grid(32 * 28, 2);                                 // 896 x 2
    conv_kernel<<<grid, 256, 0, stream>>>(wt2, xp, bias, Mp, yzp, out);
}

// Round 6
// 116.352 us; speedup vs baseline: 2.0535x; 1.0625x over previous
//
#include <hip/hip_runtime.h>
#include <hip/hip_bf16.h>

// Geometry: B=32, Cin=128, Cout=256, H=W=56, K=3, pad=1, stride=1
// Implicit GEMM: M = B*H*Wpad(64), N = 256, K = 9 taps * 128 cin
//
// xpad layout (NHWC, swizzled): per (b,hh) a 16KB row-blob:
//   byte(w, c) = w*256 + ((c*2) ^ ((w&7)<<4)),  w in [0,64), c in [0,128)
// wt2 layout: per (r, kc) a 16KB blob = two 8KB nh-halves, 64 rows of 128B
//   pairing n and n+64: byte = nh*8192 + rr*128 + (((n>>6&1)*64 + k2) ^ ((rr&7)<<4))
// Swizzles are involutions; conv stages with global_load_lds (LINEAR dest)
// and reads with the same formula (rule #21).
//
// conv: 512 thr / 8 waves (2m x 4n), block tile 256m(4 h-rows) x 256n,
// per-wave 128m x 64n -> 12 ds_read_b128 per 32 MFMA (ratio 2.67 vs 2.0).
// A resident 96KB (6 row-blobs), B dbuf 2x16KB; LDS 128KB, 1 block/CU.

typedef __attribute__((ext_vector_type(8))) __bf16 bf16x8;
typedef __attribute__((ext_vector_type(4))) float f32x4;
typedef __attribute__((ext_vector_type(8))) unsigned short u16x8;

#define WT2_ELEMS (9 * 4 * 2 * 4096)     // 294,912 u16 = 576 KB
#define XP_ELEMS  (32 * 58 * 8192)       // 15,204,352 u16 = ~30.4 MB

__device__ __forceinline__ void gload_lds16(const void* g, void* l) {
    __builtin_amdgcn_global_load_lds(
        (const __attribute__((address_space(1))) void*)g,
        (__attribute__((address_space(3))) void*)l, 16, 0, 0);
}

// ---- weight prep: w[cout][cin][3][3] - wz -> wt2 blobs (swizzle-baked) ----
__global__ void wprep_kernel(const float* __restrict__ w, const float* __restrict__ wzp,
                             unsigned short* __restrict__ wt2) {
    int t = blockIdx.x * 256 + threadIdx.x;      // < 294912
    int blobi = t >> 12;                         // (r*4+kc)*2 + nh
    int e = t & 4095;
    int byte = e * 2;
    int rr = byte >> 7;                          // row 0..63
    int slot = byte & 127;
    int us = slot ^ ((rr & 7) << 4);             // un-swizzle
    int hi = (us >> 6) & 1;
    int kl = (us & 63) >> 1;                     // k within chunk 0..31
    int nh = blobi & 1;
    int s  = blobi >> 1;
    int kc = s & 3, r = s >> 2;
    int n = nh * 128 + hi * 64 + rr;
    int k = kc * 32 + kl;
    float v = w[(size_t)n * 1152 + k * 9 + r] - *wzp;
    wt2[t] = (unsigned short)(__float_as_uint(v) >> 16);   // exact (small ints)
}

// ---- x prep: NCHW -> swizzled padded NHWC bf16 ----
__global__ void xprep_kernel(const float* __restrict__ x, const float* __restrict__ xzp,
                             unsigned short* __restrict__ xp) {
    int bhh = blockIdx.x;                        // b*58 + hh
    int b = bhh / 58, hh = bhh % 58;
    int t = threadIdx.x;
    char* blob = (char*)(xp + (size_t)bhh * 8192);
    if (hh == 0 || hh == 57) {
        u16x8 z = {0, 0, 0, 0, 0, 0, 0, 0};
#pragma unroll
        for (int i = 0; i < 4; ++i)
            *(u16x8*)(blob + (i * 256 + t) * 16) = z;
        return;
    }
    int h = hh - 1;
    float xz = *xzp;
    const float* xb = x + (size_t)b * 128 * 3136 + h * 56;   // + c*3136 + w
#pragma unroll
    for (int i = 0; i < 4; ++i) {
        int chunk = i * 256 + t;                 // 0..1023
        int byte = chunk * 16;
        int w = byte >> 8;                       // 0..63
        int slot = byte & 255;
        int c2 = slot ^ ((w & 7) << 4);          // un-swizzle -> source c
        int c0 = c2 >> 1;
        int wsrc = w - 1;
        bool valid = (unsigned)wsrc < 56u;
        u16x8 v;
#pragma unroll
        for (int j = 0; j < 8; ++j) {
            float f = valid ? (xb[(size_t)(c0 + j) * 3136 + wsrc] - xz) : 0.0f;
            v[j] = (unsigned short)(__float_as_uint(f) >> 16);
        }
        *(u16x8*)(blob + byte) = v;
    }
}

// ---- main conv ----
__global__ __launch_bounds__(512, 2)
void conv_kernel(const unsigned short* __restrict__ wt2,
                 const unsigned short* __restrict__ xp,
                 const float* __restrict__ bias,
                 const float* __restrict__ Mp,
                 const float* __restrict__ yzp,
                 float* __restrict__ out) {
    __shared__ __align__(1024) char smem[131072];    // A 96KB + B 2x16KB
    char* As = smem;
    char* Bs = smem + 98304;

    const int tid = threadIdx.x;
    const int lane = tid & 63;
    const int wid = tid >> 6;                        // 0..7
    const int l15 = lane & 15, lg = lane >> 4;
    const int wm = wid >> 2;                         // 0..1: which h-row pair
    const int wn = wid & 3;                          // 0..3: which 64-cout slice
    const int bx = blockIdx.x;                       // b*14 + h-group
    const int b = bx / 14;
    const int h0 = (bx % 14) * 4;                    // 4 output rows per block

    // ---- prologue: A = 6 row-blobs (96KB), B step 0 (16KB) ----
    const char* agbase = (const char*)xp + (size_t)(b * 58 + h0) * 16384;
    const char* wgbase = (const char*)wt2;
#pragma unroll
    for (int i = 0; i < 12; ++i) {
        int off = i * 8192 + wid * 1024;
        gload_lds16(agbase + off + lane * 16, As + off);
    }
#pragma unroll
    for (int j = 0; j < 2; ++j) {
        int off = j * 8192 + wid * 1024;
        gload_lds16(wgbase + off + lane * 16, Bs + off);
    }

    f32x4 acc[8][4];
#pragma unroll
    for (int i = 0; i < 8; ++i)
#pragma unroll
        for (int j = 0; j < 4; ++j)
            acc[i][j] = (f32x4){0.f, 0.f, 0.f, 0.f};

    __syncthreads();                                 // A + B0 staged

#pragma unroll
    for (int kh = 0; kh < 3; ++kh) {
#pragma unroll
        for (int kw = 0; kw < 3; ++kw) {
#pragma unroll
            for (int kc = 0; kc < 4; ++kc) {
                const int sidx = (kh * 3 + kw) * 4 + kc;
                // prefetch next B tile (16KB) into the other buffer
                if (sidx < 35) {
                    const char* src = wgbase + (size_t)(sidx + 1) * 16384;
                    char* dst = Bs + ((sidx + 1) & 1) * 16384;
                    gload_lds16(src + wid * 1024 + lane * 16, dst + wid * 1024);
                    gload_lds16(src + 8192 + wid * 1024 + lane * 16,
                                dst + 8192 + wid * 1024);
                }
                // B fragments (4 x 16n for this wave's 64-cout slice)
                bf16x8 bfr[4];
#pragma unroll
                for (int fn = 0; fn < 4; ++fn) {
                    int rr = fn * 16 + l15;
                    int bbyte = (sidx & 1) * 16384 + (wn >> 1) * 8192 + rr * 128 +
                                (((wn & 1) * 64 + lg * 16) ^ ((rr & 7) << 4));
                    bfr[fn] = *(const bf16x8*)(Bs + bbyte);
                }
                // A fragments: 8 x 16m (2 h-rows x 64w), swizzled read
#pragma unroll
                for (int fm = 0; fm < 8; ++fm) {
                    int w = (fm & 3) * 16 + l15 + kw;
                    int wc = w > 63 ? 63 : w;        // clamped lanes are dead outputs
                    int row = wm * 2 + (fm >> 2) + kh;
                    int abyte = row * 16384 + wc * 256 +
                                ((kc * 64 + lg * 16) ^ ((wc & 7) << 4));
                    bf16x8 a = *(const bf16x8*)(As + abyte);
#pragma unroll
                    for (int fn = 0; fn < 4; ++fn)
                        acc[fm][fn] = __builtin_amdgcn_mfma_f32_16x16x32_bf16(
                            a, bfr[fn], acc[fm][fn], 0, 0, 0);
                }
                __syncthreads();                     // drain prefetch + WAR guard
            }
        }
    }

    // ---- epilogue: requantize + ReLU + round ----
    const float Mv = *Mp;
    const float yzv = *yzp;
#pragma unroll
    for (int fn = 0; fn < 4; ++fn) {
        const int cout = wn * 64 + fn * 16 + l15;
        const float bv = bias[cout];
#pragma unroll
        for (int fm = 0; fm < 8; ++fm) {
            const int h = h0 + wm * 2 + (fm >> 2);
            const size_t rowb = ((size_t)(b * 256 + cout) * 56 + h) * 56;
#pragma unroll
            for (int reg = 0; reg < 4; ++reg) {
                int w = (fm & 3) * 16 + lg * 4 + reg;
                if (w < 56) {
                    float v = (acc[fm][fn][reg] + bv) * Mv + yzv;
                    v = fmaxf(v, yzv);
                    out[rowb + w] = rintf(v);
                }
            }
        }
    }
}

extern "C" void kernel_launch(void* const* d_in, const int* in_sizes, int n_in,
                              void* d_out, int out_size, void* d_ws, size_t ws_size,
                              hipStream_t stream) {
    const float* x    = (const float*)d_in[0];
    const float* w    = (const float*)d_in[1];
    const float* bias = (const float*)d_in[2];
    const float* Mp   = (const float*)d_in[3];
    const float* xzp  = (const float*)d_in[4];
    const float* wzp  = (const float*)d_in[5];
    const float* yzp  = (const float*)d_in[6];
    float* out = (float*)d_out;

    unsigned short* wt2 = (unsigned short*)d_ws;           // 576 KB
    unsigned short* xp  = wt2 + WT2_ELEMS;                 // ~30.4 MB

    wprep_kernel<<<WT2_ELEMS / 256, 256, 0, stream>>>(w, wzp, wt2);
    xprep_kernel<<<32 * 58, 256, 0, stream>>>(x, xzp, xp);

    conv_kernel<<<32 * 14, 512, 0, stream>>>(wt2, xp, bias, Mp, yzp, out);
}